// Round 1
// baseline (86.770 us; speedup 1.0000x reference)
//
#include <hip/hip_runtime.h>
#include <hip/hip_bf16.h>

// LUT build: crf_t[k*3 + c] = f0[k] + sum_d weight[c][d] * basis[d][k]
__global__ void emor_crf_build(const float* __restrict__ f0,
                               const float* __restrict__ basis,
                               const float* __restrict__ weight,
                               float* __restrict__ crf_t) {
    int k = blockIdx.x * blockDim.x + threadIdx.x;
    if (k >= 1024) return;
    float b[11];
#pragma unroll
    for (int d = 0; d < 11; ++d) b[d] = basis[d * 1024 + k];
    float f = f0[k];
#pragma unroll
    for (int c = 0; c < 3; ++c) {
        float acc = 0.0f;
#pragma unroll
        for (int d = 0; d < 11; ++d) acc += weight[c * 11 + d] * b[d];
        crf_t[k * 3 + c] = f + acc;
    }
}

__device__ __forceinline__ float emor_lerp(float h, float e, int c,
                                           const float* __restrict__ lut) {
    float u   = fminf(fmaxf(h * e, 0.0f), 1.0f);
    float pos = u * 1023.0f;
    float fidx = floorf(pos);
    fidx = fminf(fidx, 1022.0f);           // u >= 0 so floor >= 0 already
    int   idx  = (int)fidx;
    float frac = pos - fidx;
    float v0 = lut[idx * 3 + c];
    float v1 = lut[idx * 3 + c + 3];
    return v0 + frac * (v1 - v0);
}

__global__ void emor_apply(const float* __restrict__ hdr,
                           const float* __restrict__ expo,
                           const float* __restrict__ crf_t,
                           float* __restrict__ out,
                           long long n_flat) {
    __shared__ float lut[3072];
    for (int i = threadIdx.x; i < 3072; i += blockDim.x) lut[i] = crf_t[i];
    __syncthreads();

    float e = expo[0];
    long long tid    = (long long)blockIdx.x * blockDim.x + threadIdx.x;
    long long stride = (long long)gridDim.x * blockDim.x * 4;

    for (long long i = tid * 4; i < n_flat; i += stride) {
        float4 h = *reinterpret_cast<const float4*>(hdr + i);
        int c0 = (int)(i % 3);
        int c1 = c0 + 1; if (c1 == 3) c1 = 0;
        int c2 = c1 + 1; if (c2 == 3) c2 = 0;
        int c3 = c2 + 1; if (c3 == 3) c3 = 0;
        float4 r;
        r.x = emor_lerp(h.x, e, c0, lut);
        r.y = emor_lerp(h.y, e, c1, lut);
        r.z = emor_lerp(h.z, e, c2, lut);
        r.w = emor_lerp(h.w, e, c3, lut);
        *reinterpret_cast<float4*>(out + i) = r;
    }
}

extern "C" void kernel_launch(void* const* d_in, const int* in_sizes, int n_in,
                              void* d_out, int out_size, void* d_ws, size_t ws_size,
                              hipStream_t stream) {
    const float* hdr    = (const float*)d_in[0];   // (N_PIXELS, 3)
    const float* expo   = (const float*)d_in[1];   // (1,)
    const float* f0     = (const float*)d_in[2];   // (1, 1024)
    const float* basis  = (const float*)d_in[3];   // (11, 1024)
    const float* weight = (const float*)d_in[4];   // (3, 11)
    float* out  = (float*)d_out;                   // (N_PIXELS, 3)
    float* crf_t = (float*)d_ws;                   // 3072 floats = 12 KB

    // Build LUT (K=1024, 3 channels) in (K,3) interleaved layout.
    emor_crf_build<<<4, 256, 0, stream>>>(f0, basis, weight, crf_t);

    long long n_flat = (long long)out_size;        // 16777216*3, divisible by 4
    int block = 256;
    int grid  = 2048;                              // 256 CU * 8 blocks, grid-stride
    emor_apply<<<grid, block, 0, stream>>>(hdr, expo, crf_t, out, n_flat);
}

// Round 3
// 78.268 us; speedup vs baseline: 1.1086x; 1.1086x over previous
//
#include <hip/hip_runtime.h>
#include <hip/hip_bf16.h>

typedef float f32x4 __attribute__((ext_vector_type(4)));

// Fused: each block builds the 3x1024 CRF LUT in LDS, then streams pixels.
// lut layout: (K,3) interleaved -> lut[k*3 + c]. v0/v1 for channel c are
// 12 B apart. 12 KB LDS -> full occupancy (8 blocks/CU = 96 KB).
__global__ __launch_bounds__(256) void emor_fused(
        const float* __restrict__ hdr,
        const float* __restrict__ expo,
        const float* __restrict__ f0,
        const float* __restrict__ basis,
        const float* __restrict__ weight,
        float* __restrict__ out,
        long long n_flat) {
    __shared__ float lut[3072];

    // --- LUT build: 256 threads x 4 k-values each (k = tid + 256*j, coalesced) ---
    float w[3][11];
#pragma unroll
    for (int c = 0; c < 3; ++c)
#pragma unroll
        for (int d = 0; d < 11; ++d)
            w[c][d] = weight[c * 11 + d];   // uniform address -> scalar loads

#pragma unroll
    for (int j = 0; j < 4; ++j) {
        int k = threadIdx.x + 256 * j;
        float f = f0[k];
        float a0 = f, a1 = f, a2 = f;
#pragma unroll
        for (int d = 0; d < 11; ++d) {
            float b = basis[d * 1024 + k];
            a0 = fmaf(w[0][d], b, a0);
            a1 = fmaf(w[1][d], b, a1);
            a2 = fmaf(w[2][d], b, a2);
        }
        // banks: (k*3+c)%32, stride-3 over lanes -> gcd(3,32)=1 -> conflict-free
        lut[k * 3 + 0] = a0;
        lut[k * 3 + 1] = a1;
        lut[k * 3 + 2] = a2;
    }
    __syncthreads();

    float e = expo[0];
    long long tid    = (long long)blockIdx.x * blockDim.x + threadIdx.x;
    long long stride = (long long)gridDim.x * blockDim.x * 4;

    // stride % 3 == 0 (grid divisible by 3) -> channel pattern loop-invariant
    long long i0 = tid * 4;
    int c0 = (int)(i0 % 3);
    int c1 = c0 + 1; if (c1 == 3) c1 = 0;
    int c2 = c1 + 1; if (c2 == 3) c2 = 0;
    int c3 = c2 + 1; if (c3 == 3) c3 = 0;

    for (long long i = i0; i < n_flat; i += stride) {
        f32x4 h = __builtin_nontemporal_load(
                      reinterpret_cast<const f32x4*>(hdr + i));
        f32x4 r;
        {
            float u = fminf(fmaxf(h.x * e, 0.0f), 1.0f);
            float p = u * 1023.0f;
            float fi = fminf(floorf(p), 1022.0f);
            int idx = (int)fi;
            float v0 = lut[idx * 3 + c0], v1 = lut[idx * 3 + c0 + 3];
            r.x = fmaf(p - fi, v1 - v0, v0);
        }
        {
            float u = fminf(fmaxf(h.y * e, 0.0f), 1.0f);
            float p = u * 1023.0f;
            float fi = fminf(floorf(p), 1022.0f);
            int idx = (int)fi;
            float v0 = lut[idx * 3 + c1], v1 = lut[idx * 3 + c1 + 3];
            r.y = fmaf(p - fi, v1 - v0, v0);
        }
        {
            float u = fminf(fmaxf(h.z * e, 0.0f), 1.0f);
            float p = u * 1023.0f;
            float fi = fminf(floorf(p), 1022.0f);
            int idx = (int)fi;
            float v0 = lut[idx * 3 + c2], v1 = lut[idx * 3 + c2 + 3];
            r.z = fmaf(p - fi, v1 - v0, v0);
        }
        {
            float u = fminf(fmaxf(h.w * e, 0.0f), 1.0f);
            float p = u * 1023.0f;
            float fi = fminf(floorf(p), 1022.0f);
            int idx = (int)fi;
            float v0 = lut[idx * 3 + c3], v1 = lut[idx * 3 + c3 + 3];
            r.w = fmaf(p - fi, v1 - v0, v0);
        }
        __builtin_nontemporal_store(r, reinterpret_cast<f32x4*>(out + i));
    }
}

extern "C" void kernel_launch(void* const* d_in, const int* in_sizes, int n_in,
                              void* d_out, int out_size, void* d_ws, size_t ws_size,
                              hipStream_t stream) {
    const float* hdr    = (const float*)d_in[0];   // (N_PIXELS, 3)
    const float* expo   = (const float*)d_in[1];   // (1,)
    const float* f0     = (const float*)d_in[2];   // (1, 1024)
    const float* basis  = (const float*)d_in[3];   // (11, 1024)
    const float* weight = (const float*)d_in[4];   // (3, 11)
    float* out = (float*)d_out;                    // (N_PIXELS, 3)

    long long n_flat = (long long)out_size;        // 50331648, divisible by 4
    int block = 256;
    int grid  = 2046;  // divisible by 3 -> stride%3==0; ~8 blocks/CU
    emor_fused<<<grid, block, 0, stream>>>(hdr, expo, f0, basis, weight, out, n_flat);
}